// Round 10
// baseline (126.737 us; speedup 1.0000x reference)
//
#include <hip/hip_runtime.h>

#define N_NODES 100000
#define N_EDGES 1600000
#define TILES 6250           // 100000/16

#define NPB 128              // nodes per bucket
#define NB 782               // ceil(100000/128)
#define SUBS 256             // binning blocks; 6250 edges each
#define CAP 14               // slots per (sub,bucket); mean 8, P(>14)~1.7%
#define OVF_CAP 16384
#define LISTCAP 3712         // SUBS*CAP + overflow slack

typedef __attribute__((ext_vector_type(8))) short short8;
typedef __attribute__((ext_vector_type(4))) float f32x4;

static __device__ __forceinline__ unsigned short f2bf(float f) {
    unsigned int u = __float_as_uint(f);
    unsigned int r = (u + 0x7fffu + ((u >> 16) & 1u)) >> 16;  // RNE
    return (unsigned short)r;
}
static __device__ __forceinline__ float bfl(unsigned int u) {
    return __uint_as_float(u << 16);
}
static __device__ __forceinline__ float bfh(unsigned int u) {
    return __uint_as_float(u & 0xffff0000u);
}

// g = bf16(feat @ W^T). Verified rounds 6-9 (absmax 0.125). A/B frags share
// the k-index formula (consistent k-permutation cancels); C/D per m89.
__global__ __launch_bounds__(256) void gcn_gemm(
    const float* __restrict__ feat, const float* __restrict__ W,
    unsigned int* __restrict__ g32) {
    int l = threadIdx.x & 63, wv = threadIdx.x >> 6;
    int r = l & 15, c = l >> 4;

    short8 bf[4][2];
#pragma unroll
    for (int t = 0; t < 4; ++t)
#pragma unroll
        for (int s = 0; s < 2; ++s) {
            const float* wp = W + (16 * t + r) * 64 + 32 * s + c * 8;
            float4 w0 = *(const float4*)wp;
            float4 w1 = *(const float4*)(wp + 4);
            short8 f;
            f[0] = (short)f2bf(w0.x); f[1] = (short)f2bf(w0.y);
            f[2] = (short)f2bf(w0.z); f[3] = (short)f2bf(w0.w);
            f[4] = (short)f2bf(w1.x); f[5] = (short)f2bf(w1.y);
            f[6] = (short)f2bf(w1.z); f[7] = (short)f2bf(w1.w);
            bf[t][s] = f;
        }

    int tile0 = (blockIdx.x * 4 + wv) * 4;
#pragma unroll
    for (int ti = 0; ti < 4; ++ti) {
        int tile = tile0 + ti;
        if (tile >= TILES) break;
        int m0 = tile * 16;
        f32x4 acc0 = {0,0,0,0}, acc1 = {0,0,0,0}, acc2 = {0,0,0,0}, acc3 = {0,0,0,0};
#pragma unroll
        for (int s = 0; s < 2; ++s) {
            const float* ap = feat + (m0 + r) * 64 + 32 * s + c * 8;
            float4 a0 = *(const float4*)ap;
            float4 a1 = *(const float4*)(ap + 4);
            short8 af;
            af[0] = (short)f2bf(a0.x); af[1] = (short)f2bf(a0.y);
            af[2] = (short)f2bf(a0.z); af[3] = (short)f2bf(a0.w);
            af[4] = (short)f2bf(a1.x); af[5] = (short)f2bf(a1.y);
            af[6] = (short)f2bf(a1.z); af[7] = (short)f2bf(a1.w);
            acc0 = __builtin_amdgcn_mfma_f32_16x16x32_bf16(af, bf[0][s], acc0, 0, 0, 0);
            acc1 = __builtin_amdgcn_mfma_f32_16x16x32_bf16(af, bf[1][s], acc1, 0, 0, 0);
            acc2 = __builtin_amdgcn_mfma_f32_16x16x32_bf16(af, bf[2][s], acc2, 0, 0, 0);
            acc3 = __builtin_amdgcn_mfma_f32_16x16x32_bf16(af, bf[3][s], acc3, 0, 0, 0);
        }
#pragma unroll
        for (int t = 0; t < 4; ++t) {
            f32x4 a = (t == 0) ? acc0 : (t == 1) ? acc1 : (t == 2) ? acc2 : acc3;
#pragma unroll
            for (int reg = 0; reg < 4; ++reg) {
                float d = a[reg];
                float o = __shfl_xor(d, 1);
                if (!(l & 1)) {
                    int m = m0 + c * 4 + reg;
                    int n = 16 * t + r;
                    g32[(m * 64 + n) >> 1] =
                        (unsigned int)f2bf(d) | ((unsigned int)f2bf(o) << 16);
                }
            }
        }
    }
}

// LDS-staged binning. Round-9 lesson: global random scatter stores fill each
// region line slowly in random order -> ~5x dirty-line writebacks (56 MB) and
// a latency-bound atomic->store chain. Fix: bin into LDS (cnt[782] +
// data[782][14] = 47 KB), then FLUSH with dense coalesced stores -- every
// region line is written once (write-amp ~1x), and in-loop atomics are LDS.
__global__ __launch_bounds__(512) void gcn_bin(
    const int* __restrict__ src, const int* __restrict__ dst,
    unsigned int* __restrict__ cursor, unsigned int* __restrict__ region,
    unsigned int* __restrict__ ovf_cnt, uint2* __restrict__ ovf) {
    __shared__ unsigned int cnt[NB];
    __shared__ unsigned int data[NB][CAP];
    int sub = blockIdx.x;
    for (int i = threadIdx.x; i < NB; i += 512) cnt[i] = 0;
    __syncthreads();

    int base = sub * (N_EDGES / SUBS);          // 6250 edges per block
    int end = base + (N_EDGES / SUBS);
    for (int i = base + threadIdx.x; i < end; i += 512) {
        int s = src[i];
        int d = dst[i];
        int bk = d >> 7;
        unsigned int c = atomicAdd(&cnt[bk], 1u);
        if (c < CAP) {
            data[bk][c] = ((unsigned int)(d & 127) << 17) | (unsigned int)s;
        } else {
            unsigned int o = atomicAdd(ovf_cnt, 1u);
            if (o < OVF_CAP) ovf[o] = make_uint2((unsigned int)s, (unsigned int)d);
        }
    }
    __syncthreads();

    // dense, coalesced, write-once flush
    unsigned int rbase = (unsigned int)sub * NB * CAP;
    for (int idx = threadIdx.x; idx < NB * CAP; idx += 512) {
        int bk = idx / CAP, slot = idx - bk * CAP;
        unsigned int c = cnt[bk];
        if (slot < (int)(c < CAP ? c : CAP))
            region[rbase + (unsigned int)idx] = data[bk][slot];
    }
    for (int bk = threadIdx.x; bk < NB; bk += 512)
        cursor[sub * NB + bk] = cnt[bk];
}

// One block per bucket (128 nodes). Counting-sort entries by node in LDS,
// then per-node gather: 16-lane groups load one transformed 128B row per
// entry, register accumulate, shfl-reduce, bias+relu+float4 store.
__global__ __launch_bounds__(512) void gcn_gather3(
    const uint2* __restrict__ g64, const unsigned int* __restrict__ cursor,
    const unsigned int* __restrict__ region, const unsigned int* __restrict__ ovf_cnt,
    const uint2* __restrict__ ovf, const float* __restrict__ bias,
    float* __restrict__ out) {
    __shared__ unsigned int list[LISTCAP];
    __shared__ unsigned int sorted[LISTCAP];
    __shared__ unsigned int scnt[SUBS], soff[SUBS];
    __shared__ unsigned int cnt2[NPB], off2[NPB], cur2[NPB];
    __shared__ unsigned int ltot;

    int b = blockIdx.x;
    int tid = threadIdx.x;

    if (tid < SUBS) {
        unsigned int c = cursor[(unsigned)tid * NB + b];
        scnt[tid] = c < CAP ? c : CAP;
    }
    if (tid < NPB) cnt2[tid] = 0;
    __syncthreads();
    if (tid < SUBS) soff[tid] = scnt[tid];
    __syncthreads();
    for (int off = 1; off < SUBS; off <<= 1) {
        unsigned int t = 0;
        if (tid < SUBS && tid >= off) t = soff[tid - off];
        __syncthreads();
        if (tid < SUBS) soff[tid] += t;
        __syncthreads();
    }
    if (tid == 0) ltot = soff[SUBS - 1];
    __syncthreads();

    for (int idx = tid; idx < SUBS * CAP; idx += 512) {
        int s = idx / CAP, slot = idx - s * CAP;
        if (slot < (int)scnt[s])
            list[soff[s] - scnt[s] + slot] =
                region[((unsigned)s * NB + b) * CAP + slot];
    }
    unsigned int oc = *ovf_cnt;
    if (oc > OVF_CAP) oc = OVF_CAP;
    for (unsigned int i = tid; i < oc; i += 512) {
        uint2 e = ovf[i];
        if ((int)(e.y >> 7) == b) {
            unsigned int p = atomicAdd(&ltot, 1u);
            if (p < LISTCAP) list[p] = ((e.y & 127u) << 17) | e.x;
        }
    }
    __syncthreads();
    unsigned int T = ltot < LISTCAP ? ltot : LISTCAP;

    for (unsigned int i = tid; i < T; i += 512)
        atomicAdd(&cnt2[list[i] >> 17], 1u);
    __syncthreads();
    if (tid < NPB) off2[tid] = cnt2[tid];
    __syncthreads();
    for (int off = 1; off < NPB; off <<= 1) {
        unsigned int t = 0;
        if (tid < NPB && tid >= off) t = off2[tid - off];
        __syncthreads();
        if (tid < NPB) off2[tid] += t;
        __syncthreads();
    }
    if (tid < NPB) cur2[tid] = off2[tid] - cnt2[tid];
    __syncthreads();
    for (unsigned int i = tid; i < T; i += 512) {
        unsigned int v = list[i];
        unsigned int p = atomicAdd(&cur2[v >> 17], 1u);
        if (p < LISTCAP) sorted[p] = v & 0x1FFFFu;
    }
    __syncthreads();

    int wv = tid >> 6, l = tid & 63, grp = l >> 4, k = l & 15;
    for (int n = 0; n < 16; ++n) {
        int dl = wv * 16 + n;
        int node = b * NPB + dl;
        if (node >= N_NODES) break;   // wave-uniform
        unsigned int start = off2[dl] - cnt2[dl];
        int cnt = (int)cnt2[dl];
        float a0 = 0.f, a1 = 0.f, a2 = 0.f, a3 = 0.f;
        int j = 0;
        for (; j + 8 <= cnt; j += 8) {
            unsigned int s0 = sorted[start + j + grp];
            unsigned int s1 = sorted[start + j + 4 + grp];
            uint2 w0 = g64[s0 * 16 + k];
            uint2 w1 = g64[s1 * 16 + k];
            a0 += bfl(w0.x); a1 += bfh(w0.x); a2 += bfl(w0.y); a3 += bfh(w0.y);
            a0 += bfl(w1.x); a1 += bfh(w1.x); a2 += bfl(w1.y); a3 += bfh(w1.y);
        }
        for (; j < cnt; j += 4) {
            if (j + grp < cnt) {
                unsigned int s0 = sorted[start + j + grp];
                uint2 w = g64[s0 * 16 + k];
                a0 += bfl(w.x); a1 += bfh(w.x); a2 += bfl(w.y); a3 += bfh(w.y);
            }
        }
        a0 += __shfl_xor(a0, 16); a0 += __shfl_xor(a0, 32);
        a1 += __shfl_xor(a1, 16); a1 += __shfl_xor(a1, 32);
        a2 += __shfl_xor(a2, 16); a2 += __shfl_xor(a2, 32);
        a3 += __shfl_xor(a3, 16); a3 += __shfl_xor(a3, 32);
        if (l < 16) {
            float4 b4 = *(const float4*)(bias + 4 * l);
            float4 o;
            o.x = fmaxf(a0 + b4.x, 0.0f);
            o.y = fmaxf(a1 + b4.y, 0.0f);
            o.z = fmaxf(a2 + b4.z, 0.0f);
            o.w = fmaxf(a3 + b4.w, 0.0f);
            *(float4*)(out + node * 64 + 4 * l) = o;
        }
    }
}

extern "C" void kernel_launch(void* const* d_in, const int* in_sizes, int n_in,
                              void* d_out, int out_size, void* d_ws, size_t ws_size,
                              hipStream_t stream) {
    const float* features = (const float*)d_in[0];
    const int*   src      = (const int*)d_in[1];
    const int*   dst      = (const int*)d_in[2];
    const float* W        = (const float*)d_in[3];
    const float* b        = (const float*)d_in[4];
    float* out = (float*)d_out;

    // Workspace (u32): cursor[200192] | ovfcnt[64] | ovf[32768] |
    //                  region[2802688] | g32[3200000]  -- total 24.9 MB
    unsigned int* ws     = (unsigned int*)d_ws;
    unsigned int* cursor = ws;                       // 256*782
    unsigned int* ovfcnt = ws + 200192;
    uint2*        ovf    = (uint2*)(ws + 200256);    // 16384 uint2
    unsigned int* region = ws + 233024;              // 256*782*14
    unsigned int* g32    = ws + 3035712;             // 3.2M u32

    // cursor is fully written by gcn_bin's flush; only ovf_cnt needs zeroing.
    hipMemsetAsync(ovfcnt, 0, 64 * sizeof(unsigned int), stream);

    gcn_gemm<<<(TILES + 15) / 16, 256, 0, stream>>>(features, W, g32);
    gcn_bin<<<SUBS, 512, 0, stream>>>(src, dst, cursor, region, ovfcnt, ovf);
    gcn_gather3<<<NB, 512, 0, stream>>>((const uint2*)g32, cursor, region,
                                        ovfcnt, ovf, b, out);
}

// Round 11
// 79.232 us; speedup vs baseline: 1.5996x; 1.5996x over previous
//
#include <hip/hip_runtime.h>

#define N_NODES 100000
#define N_EDGES 1600000
#define TILES 6250           // 100000/16

#define NPB 128              // nodes per bucket
#define NB 782               // ceil(100000/128)
#define SUBS 256             // binning blocks; 6250 edges each
#define CAP 14               // slots per (sub,bucket); mean 8
#define OVF_CAP 16384
#define LOVF_CAP 512         // per-block LDS overflow buffer (E~25)
#define LISTCAP 3712         // SUBS*CAP + overflow slack

typedef __attribute__((ext_vector_type(8))) short short8;
typedef __attribute__((ext_vector_type(4))) float f32x4;

static __device__ __forceinline__ unsigned short f2bf(float f) {
    unsigned int u = __float_as_uint(f);
    unsigned int r = (u + 0x7fffu + ((u >> 16) & 1u)) >> 16;  // RNE
    return (unsigned short)r;
}
static __device__ __forceinline__ float bfl(unsigned int u) {
    return __uint_as_float(u << 16);
}
static __device__ __forceinline__ float bfh(unsigned int u) {
    return __uint_as_float(u & 0xffff0000u);
}

// g = bf16(feat @ W^T). Verified rounds 6-10 (absmax 0.125).
__global__ __launch_bounds__(256) void gcn_gemm(
    const float* __restrict__ feat, const float* __restrict__ W,
    unsigned int* __restrict__ g32) {
    int l = threadIdx.x & 63, wv = threadIdx.x >> 6;
    int r = l & 15, c = l >> 4;

    short8 bf[4][2];
#pragma unroll
    for (int t = 0; t < 4; ++t)
#pragma unroll
        for (int s = 0; s < 2; ++s) {
            const float* wp = W + (16 * t + r) * 64 + 32 * s + c * 8;
            float4 w0 = *(const float4*)wp;
            float4 w1 = *(const float4*)(wp + 4);
            short8 f;
            f[0] = (short)f2bf(w0.x); f[1] = (short)f2bf(w0.y);
            f[2] = (short)f2bf(w0.z); f[3] = (short)f2bf(w0.w);
            f[4] = (short)f2bf(w1.x); f[5] = (short)f2bf(w1.y);
            f[6] = (short)f2bf(w1.z); f[7] = (short)f2bf(w1.w);
            bf[t][s] = f;
        }

    int tile0 = (blockIdx.x * 4 + wv) * 4;
#pragma unroll
    for (int ti = 0; ti < 4; ++ti) {
        int tile = tile0 + ti;
        if (tile >= TILES) break;
        int m0 = tile * 16;
        f32x4 acc0 = {0,0,0,0}, acc1 = {0,0,0,0}, acc2 = {0,0,0,0}, acc3 = {0,0,0,0};
#pragma unroll
        for (int s = 0; s < 2; ++s) {
            const float* ap = feat + (m0 + r) * 64 + 32 * s + c * 8;
            float4 a0 = *(const float4*)ap;
            float4 a1 = *(const float4*)(ap + 4);
            short8 af;
            af[0] = (short)f2bf(a0.x); af[1] = (short)f2bf(a0.y);
            af[2] = (short)f2bf(a0.z); af[3] = (short)f2bf(a0.w);
            af[4] = (short)f2bf(a1.x); af[5] = (short)f2bf(a1.y);
            af[6] = (short)f2bf(a1.z); af[7] = (short)f2bf(a1.w);
            acc0 = __builtin_amdgcn_mfma_f32_16x16x32_bf16(af, bf[0][s], acc0, 0, 0, 0);
            acc1 = __builtin_amdgcn_mfma_f32_16x16x32_bf16(af, bf[1][s], acc1, 0, 0, 0);
            acc2 = __builtin_amdgcn_mfma_f32_16x16x32_bf16(af, bf[2][s], acc2, 0, 0, 0);
            acc3 = __builtin_amdgcn_mfma_f32_16x16x32_bf16(af, bf[3][s], acc3, 0, 0, 0);
        }
#pragma unroll
        for (int t = 0; t < 4; ++t) {
            f32x4 a = (t == 0) ? acc0 : (t == 1) ? acc1 : (t == 2) ? acc2 : acc3;
#pragma unroll
            for (int reg = 0; reg < 4; ++reg) {
                float d = a[reg];
                float o = __shfl_xor(d, 1);
                if (!(l & 1)) {
                    int m = m0 + c * 4 + reg;
                    int n = 16 * t + r;
                    g32[(m * 64 + n) >> 1] =
                        (unsigned int)f2bf(d) | ((unsigned int)f2bf(o) << 16);
                }
            }
        }
    }
}

// LDS-staged binning (round 10) + this round: NO global atomic in the hot
// loop (overflow goes to an LDS buffer, flushed once via a single
// chunk-reserving atomicAdd), explicit next-iteration prefetch, 1024 thr.
__global__ __launch_bounds__(1024) void gcn_bin(
    const int* __restrict__ src, const int* __restrict__ dst,
    unsigned int* __restrict__ cursor, unsigned int* __restrict__ region,
    unsigned int* __restrict__ ovf_cnt, uint2* __restrict__ ovf) {
    __shared__ unsigned int cnt[NB];
    __shared__ unsigned int data[NB][CAP];
    __shared__ uint2 lovf[LOVF_CAP];
    __shared__ unsigned int lovf_n, lovf_base;
    int sub = blockIdx.x;
    int tid = threadIdx.x;
    for (int i = tid; i < NB; i += 1024) cnt[i] = 0;
    if (tid == 0) lovf_n = 0;
    __syncthreads();

    int base = sub * (N_EDGES / SUBS);          // 6250 edges per block
    int end = base + (N_EDGES / SUBS);
    int i = base + tid;
    int s = 0, d = 0;
    if (i < end) { s = src[i]; d = dst[i]; }
    while (i < end) {
        int inext = i + 1024;
        int sn = 0, dn = 0;
        if (inext < end) { sn = src[inext]; dn = dst[inext]; }  // prefetch
        int bk = d >> 7;
        unsigned int c = atomicAdd(&cnt[bk], 1u);               // LDS
        if (c < CAP) {
            data[bk][c] = ((unsigned int)(d & 127) << 17) | (unsigned int)s;
        } else {
            unsigned int o = atomicAdd(&lovf_n, 1u);            // LDS
            if (o < LOVF_CAP) lovf[o] = make_uint2((unsigned int)s, (unsigned int)d);
        }
        i = inext; s = sn; d = dn;
    }
    __syncthreads();

    // dense, coalesced, write-once flush
    unsigned int rbase = (unsigned int)sub * NB * CAP;
    for (int idx = tid; idx < NB * CAP; idx += 1024) {
        int bk = idx / CAP, slot = idx - bk * CAP;
        unsigned int c = cnt[bk];
        if (slot < (int)(c < CAP ? c : CAP))
            region[rbase + (unsigned int)idx] = data[bk][slot];
    }
    for (int bk = tid; bk < NB; bk += 1024)
        cursor[sub * NB + bk] = cnt[bk];

    // one global atomic per block reserves an overflow chunk
    unsigned int n = lovf_n < LOVF_CAP ? lovf_n : LOVF_CAP;
    if (tid == 0) lovf_base = atomicAdd(ovf_cnt, n);
    __syncthreads();
    for (unsigned int t = tid; t < n; t += 1024) {
        unsigned int p = lovf_base + t;
        if (p < OVF_CAP) ovf[p] = lovf[t];
    }
}

// One block per bucket (128 nodes). Counting-sort entries by node in LDS,
// then: each 16-LANE GROUP owns one node (4 nodes concurrently per wave,
// no cross-group reduce). Lane k accumulates feats 4k..4k+3; unroll-4 puts
// 4 independent 128B row-loads in flight. Epilogue float4 store per group.
__global__ __launch_bounds__(512) void gcn_gather3(
    const uint2* __restrict__ g64, const unsigned int* __restrict__ cursor,
    const unsigned int* __restrict__ region, const unsigned int* __restrict__ ovf_cnt,
    const uint2* __restrict__ ovf, const float* __restrict__ bias,
    float* __restrict__ out) {
    __shared__ unsigned int list[LISTCAP];
    __shared__ unsigned int sorted[LISTCAP];
    __shared__ unsigned int scnt[SUBS], soff[SUBS];
    __shared__ unsigned int cnt2[NPB], off2[NPB], cur2[NPB];
    __shared__ unsigned int ltot;

    int b = blockIdx.x;
    int tid = threadIdx.x;

    if (tid < SUBS) {
        unsigned int c = cursor[(unsigned)tid * NB + b];
        scnt[tid] = c < CAP ? c : CAP;
    }
    if (tid < NPB) cnt2[tid] = 0;
    __syncthreads();
    if (tid < SUBS) soff[tid] = scnt[tid];
    __syncthreads();
    for (int off = 1; off < SUBS; off <<= 1) {
        unsigned int t = 0;
        if (tid < SUBS && tid >= off) t = soff[tid - off];
        __syncthreads();
        if (tid < SUBS) soff[tid] += t;
        __syncthreads();
    }
    if (tid == 0) ltot = soff[SUBS - 1];
    __syncthreads();

    for (int idx = tid; idx < SUBS * CAP; idx += 512) {
        int s = idx / CAP, slot = idx - s * CAP;
        if (slot < (int)scnt[s])
            list[soff[s] - scnt[s] + slot] =
                region[((unsigned)s * NB + b) * CAP + slot];
    }
    unsigned int oc = *ovf_cnt;
    if (oc > OVF_CAP) oc = OVF_CAP;
    for (unsigned int i = tid; i < oc; i += 512) {
        uint2 e = ovf[i];
        if ((int)(e.y >> 7) == b) {
            unsigned int p = atomicAdd(&ltot, 1u);
            if (p < LISTCAP) list[p] = ((e.y & 127u) << 17) | e.x;
        }
    }
    __syncthreads();
    unsigned int T = ltot < LISTCAP ? ltot : LISTCAP;

    for (unsigned int i = tid; i < T; i += 512)
        atomicAdd(&cnt2[list[i] >> 17], 1u);
    __syncthreads();
    if (tid < NPB) off2[tid] = cnt2[tid];
    __syncthreads();
    for (int off = 1; off < NPB; off <<= 1) {
        unsigned int t = 0;
        if (tid < NPB && tid >= off) t = off2[tid - off];
        __syncthreads();
        if (tid < NPB) off2[tid] += t;
        __syncthreads();
    }
    if (tid < NPB) cur2[tid] = off2[tid] - cnt2[tid];
    __syncthreads();
    for (unsigned int i = tid; i < T; i += 512) {
        unsigned int v = list[i];
        unsigned int p = atomicAdd(&cur2[v >> 17], 1u);
        if (p < LISTCAP) sorted[p] = v & 0x1FFFFu;
    }
    __syncthreads();

    // group-per-node gather: wave wv handles nodes wv*16 + nb*4 + grp
    int wv = tid >> 6, l = tid & 63, grp = l >> 4, k = l & 15;
#pragma unroll
    for (int nb = 0; nb < 4; ++nb) {
        int dl = wv * 16 + nb * 4 + grp;
        int node = b * NPB + dl;
        if (node < N_NODES) {
            unsigned int start = off2[dl] - cnt2[dl];
            int cnt = (int)cnt2[dl];
            float a0 = 0.f, a1 = 0.f, a2 = 0.f, a3 = 0.f;
#pragma unroll 4
            for (int j = 0; j < cnt; ++j) {
                unsigned int s0 = sorted[start + j];   // LDS broadcast in group
                uint2 w = g64[s0 * 16 + k];            // 128B line per group
                a0 += bfl(w.x); a1 += bfh(w.x); a2 += bfl(w.y); a3 += bfh(w.y);
            }
            float4 b4 = *(const float4*)(bias + 4 * k);
            float4 o;
            o.x = fmaxf(a0 + b4.x, 0.0f);
            o.y = fmaxf(a1 + b4.y, 0.0f);
            o.z = fmaxf(a2 + b4.z, 0.0f);
            o.w = fmaxf(a3 + b4.w, 0.0f);
            *(float4*)(out + node * 64 + 4 * k) = o;
        }
    }
}

extern "C" void kernel_launch(void* const* d_in, const int* in_sizes, int n_in,
                              void* d_out, int out_size, void* d_ws, size_t ws_size,
                              hipStream_t stream) {
    const float* features = (const float*)d_in[0];
    const int*   src      = (const int*)d_in[1];
    const int*   dst      = (const int*)d_in[2];
    const float* W        = (const float*)d_in[3];
    const float* b        = (const float*)d_in[4];
    float* out = (float*)d_out;

    // Workspace (u32): cursor[200192] | ovfcnt[64] | ovf[32768] |
    //                  region[2802688] | g32[3200000]  -- total 24.9 MB
    unsigned int* ws     = (unsigned int*)d_ws;
    unsigned int* cursor = ws;                       // 256*782
    unsigned int* ovfcnt = ws + 200192;
    uint2*        ovf    = (uint2*)(ws + 200256);    // 16384 uint2
    unsigned int* region = ws + 233024;              // 256*782*14
    unsigned int* g32    = ws + 3035712;             // 3.2M u32

    hipMemsetAsync(ovfcnt, 0, 64 * sizeof(unsigned int), stream);

    gcn_gemm<<<(TILES + 15) / 16, 256, 0, stream>>>(features, W, g32);
    gcn_bin<<<SUBS, 1024, 0, stream>>>(src, dst, cursor, region, ovfcnt, ovf);
    gcn_gather3<<<NB, 512, 0, stream>>>((const uint2*)g32, cursor, region,
                                        ovfcnt, ovf, b, out);
}